// Round 1
// baseline (135.710 us; speedup 1.0000x reference)
//
#include <hip/hip_runtime.h>
#include <math.h>
#include <stdint.h>

#define N_NODES 8192
#define D 7
#define K 32
#define NTHREADS 256
#define CPT 32            // candidates per thread = N_NODES / NTHREADS
#define CAP 512           // candidate buffer capacity (expected M ~ 150)

// ---------------------------------------------------------------------------
// Kernel 1: out = clip(feat @ W^T, -1, 1), sq = rowsum(feat^2)
// ---------------------------------------------------------------------------
__global__ __launch_bounds__(NTHREADS)
void precompute_kernel(const float* __restrict__ x, const float* __restrict__ W,
                       float* __restrict__ outb, float* __restrict__ sqb)
{
    int n = blockIdx.x * NTHREADS + threadIdx.x;
    float4 v0 = *reinterpret_cast<const float4*>(x + n * 8);
    float4 v1 = *reinterpret_cast<const float4*>(x + n * 8 + 4);
    float f[D] = {v0.x, v0.y, v0.z, v0.w, v1.x, v1.y, v1.z};
    float sq = 0.f;
#pragma unroll
    for (int c = 0; c < D; ++c) sq += f[c] * f[c];
    sqb[n] = sq;
#pragma unroll
    for (int r = 0; r < D; ++r) {
        float acc = 0.f;
#pragma unroll
        for (int c = 0; c < D; ++c) acc += f[c] * W[r * D + c];
        acc = fminf(fmaxf(acc, -1.f), 1.f);
        outb[n * D + r] = acc;
    }
}

// ---------------------------------------------------------------------------
// Kernel 2: per-node exact top-32 (matching jax.lax.top_k order) + attention
// One block (256 threads) per node. Distances live in registers (32/thread,
// all index arithmetic compile-time unrolled).
// ---------------------------------------------------------------------------
__global__ __launch_bounds__(NTHREADS)
void gat_kernel(const float* __restrict__ x, const float* __restrict__ a,
                const float* __restrict__ outb, const float* __restrict__ sqb,
                float* __restrict__ dout)
{
    __shared__ unsigned long long cand[CAP];
    __shared__ float Tsh[4];
    __shared__ int   cnt;
    __shared__ float redv[4];
    __shared__ int   redi[4];

    const int i    = blockIdx.x;
    const int tid  = threadIdx.x;
    const int lane = tid & 63;
    const int wave = tid >> 6;

    // --- node-i features + sq ---
    float4 q0 = *reinterpret_cast<const float4*>(x + i * 8);
    float4 q1 = *reinterpret_cast<const float4*>(x + i * 8 + 4);
    const float fi0 = q0.x, fi1 = q0.y, fi2 = q0.z, fi3 = q0.w;
    const float fi4 = q1.x, fi5 = q1.y, fi6 = q1.z;
    const float sqi = sqb[i];

    // --- distances: thread t owns j = t + 256*c, c = 0..31 (coalesced) ---
    float dreg[CPT];
    float lmin = INFINITY;
#pragma unroll
    for (int c = 0; c < CPT; ++c) {
        int j = tid + (c << 8);
        float4 b0 = *reinterpret_cast<const float4*>(x + j * 8);
        float4 b1 = *reinterpret_cast<const float4*>(x + j * 8 + 4);
        float dot = fi0 * b0.x + fi1 * b0.y + fi2 * b0.z + fi3 * b0.w
                  + fi4 * b1.x + fi5 * b1.y + fi6 * b1.z;
        float d2 = sqi + sqb[j] - 2.0f * dot;   // same formula as reference
        d2 = fmaxf(d2, 0.0f);
        if (j == i) d2 = INFINITY;              // diagonal excluded
        dreg[c] = d2;
        lmin = fminf(lmin, d2);
    }

    // --- per-wave bitonic sort of 64 lane-minima; value at sorted pos 31 is a
    //     provable upper bound on the global 32nd-smallest ---
    {
        float v = lmin;
#pragma unroll
        for (int k = 2; k <= 64; k <<= 1) {
#pragma unroll
            for (int j = k >> 1; j > 0; j >>= 1) {
                float o   = __shfl_xor(v, j);
                bool  up  = ((lane & k) == 0);
                bool  low = ((lane & j) == 0);
                v = (low == up) ? fminf(v, o) : fmaxf(v, o);
            }
        }
        float Tw = __shfl(v, 31);
        if (lane == 0) Tsh[wave] = Tw;
        if (tid == 0) cnt = 0;
    }
    __syncthreads();
    const float T = fminf(fminf(Tsh[0], Tsh[1]), fminf(Tsh[2], Tsh[3]));

    // --- compact survivors (d <= T) into LDS as (dist_bits<<32)|idx keys ---
#pragma unroll
    for (int c = 0; c < CPT; ++c) {
        if (dreg[c] <= T) {
            int j   = tid + (c << 8);
            int pos = atomicAdd(&cnt, 1);
            if (pos < CAP) {
                cand[pos] = ((unsigned long long)__float_as_uint(dreg[c]) << 32)
                          | (unsigned)j;
            }
        }
    }
    __syncthreads();
    const int M = cnt;

    if (M <= CAP) {
        // pad + bitonic sort (ascending). u64 key compare == (dist, idx) lex order.
        const int sn = (M <= 256) ? 256 : CAP;
        for (int p = M + tid; p < sn; p += NTHREADS) cand[p] = ~0ull;
        __syncthreads();
        for (int k = 2; k <= sn; k <<= 1) {
            for (int j = k >> 1; j > 0; j >>= 1) {
                for (int p = tid; p < sn; p += NTHREADS) {
                    int q = p ^ j;
                    if (q > p) {
                        unsigned long long A = cand[p], B = cand[q];
                        bool up = ((p & k) == 0);
                        if ((A > B) == up) { cand[p] = B; cand[q] = A; }
                    }
                }
                __syncthreads();
            }
        }
    } else {
        // exact fallback (never expected): repeated lexicographic
        // "smallest (d, j) strictly greater than last extracted".
        float lastv = -1.0f; int lasti = -1;
        for (int it = 0; it < K; ++it) {
            float best = INFINITY; int bidx = 0x7fffffff;
#pragma unroll
            for (int c = 0; c < CPT; ++c) {
                int j = tid + (c << 8);
                float dv = dreg[c];
                bool gt = (dv > lastv) || (dv == lastv && j > lasti);
                if (gt && (dv < best || (dv == best && j < bidx))) {
                    best = dv; bidx = j;
                }
            }
#pragma unroll
            for (int off = 32; off > 0; off >>= 1) {
                float ov = __shfl_down(best, off);
                int   oi = __shfl_down(bidx, off);
                if (ov < best || (ov == best && oi < bidx)) { best = ov; bidx = oi; }
            }
            if (lane == 0) { redv[wave] = best; redi[wave] = bidx; }
            __syncthreads();
            float bv = redv[0]; int bi = redi[0];
#pragma unroll
            for (int w = 1; w < 4; ++w) {
                if (redv[w] < bv || (redv[w] == bv && redi[w] < bi)) {
                    bv = redv[w]; bi = redi[w];
                }
            }
            if (tid == 0)
                cand[it] = ((unsigned long long)__float_as_uint(bv) << 32) | (unsigned)bi;
            lastv = bv; lasti = bi;
            __syncthreads();
        }
    }

    // --- attention over the 32 sorted neighbors: lanes 0..31 of wave 0 ---
    if (tid < K) {
        int nk = (int)(cand[tid] & 0xffffffffu);
        float base = 0.f;
#pragma unroll
        for (int c = 0; c < D; ++c) base += outb[i * D + c] * a[c];
        float xp[D + 1];
        float s = base;
#pragma unroll
        for (int c = 0; c < D; ++c) {
            float on = outb[nk * D + c];
            xp[c] = on;
            s += on * a[D + c];
        }
        xp[D] = x[nk * 8 + 7];   // pollutant of neighbor

        float m = s;
#pragma unroll
        for (int off = 16; off > 0; off >>= 1) m = fmaxf(m, __shfl_xor(m, off, 32));
        float e = expf(s - m);
        float sum = e;
#pragma unroll
        for (int off = 16; off > 0; off >>= 1) sum += __shfl_xor(sum, off, 32);
        float att = e / sum;

        float agg[D + 1];
#pragma unroll
        for (int dd = 0; dd < D + 1; ++dd) {
            float v = att * xp[dd];
#pragma unroll
            for (int off = 16; off > 0; off >>= 1) v += __shfl_xor(v, off, 32);
            agg[dd] = v;
        }

        float* y0 = dout;
        float* y1 = dout + N_NODES * 15;
        if (tid < D) {
            float o = outb[i * D + tid];
            y0[i * 15 + tid] = o;
            y1[i * 15 + tid] = o;
        }
        if (tid < D + 1) {
            // static-index select to avoid runtime-indexed register array
            float av = 0.f;
#pragma unroll
            for (int dd = 0; dd < D + 1; ++dd) av = (tid == dd) ? agg[dd] : av;
            y0[i * 15 + D + tid] = av;
            y1[i * 15 + D + tid] = av;
        }
        if (i == N_NODES - 1) dout[2 * N_NODES * 15 + tid] = att;
    }
}

extern "C" void kernel_launch(void* const* d_in, const int* in_sizes, int n_in,
                              void* d_out, int out_size, void* d_ws, size_t ws_size,
                              hipStream_t stream) {
    (void)in_sizes; (void)n_in; (void)out_size; (void)ws_size;
    const float* x = (const float*)d_in[0];
    const float* W = (const float*)d_in[1];
    const float* a = (const float*)d_in[2];
    float* out  = (float*)d_out;
    float* outb = (float*)d_ws;                 // 8192*7 floats
    float* sqb  = outb + N_NODES * D;           // 8192 floats

    hipLaunchKernelGGL(precompute_kernel, dim3(N_NODES / NTHREADS), dim3(NTHREADS),
                       0, stream, x, W, outb, sqb);
    hipLaunchKernelGGL(gat_kernel, dim3(N_NODES), dim3(NTHREADS),
                       0, stream, x, a, outb, sqb, out);
}